// Round 5
// baseline (429.736 us; speedup 1.0000x reference)
//
#include <hip/hip_runtime.h>
#include <hip/hip_bf16.h>

// B=16, S=2048, D=64 attention w/ symmetric pad mask.
// out = [context (B*S*D fp32), attn (B*S*S fp32)] concatenated.
//
// R9: deconstruction. R5-R8 tuning plateaued at ~135us kernel vs ~50us pipe
// floors -> barrier-serialization-bound (~70 syncthreads, each draining
// vmcnt(0)). But the K/V bf16 ws is 512 KB/batch and with the XCD swizzle is
// L2-RESIDENT (1 MB per XCD's 4 MB L2) -> LDS staging protects nothing
// (m169 lesson: stage only when data doesn't cache-fit). So: NO sK, NO sVT,
// no global_load_lds, no double-buffering. QK kb-frags and PV bfrags are
// direct per-lane 16B global loads from a PLAIN (unswizzled) bf16 ws,
// 64B-coalesced, L2-hit. sP stays per-wave (lgkmcnt path only). Exactly ONE
// __syncthreads in the kernel (mask->LDS fill). 12 waves/CU free-run; TLP
// hides all latency. NT stores keep the 264 MB attn stream from evicting the
// L2 working set. Math bit-identical to R8. Fallback R4 kernel retained.
#define NBATCH 16
#define SLEN   2048
#define DIM    64
#define TQ     64
#define NTHR   256
#define NW     4
#define PANEL  128
#define NPANEL (SLEN / PANEL)   // 16
#define PROWP  136              // shorts: 128 data + 8 pad (16B-aligned rows)
// fallback (R4) layout constants
#define PROWK  72
#define PROWV  136

typedef __attribute__((ext_vector_type(8))) short bf16x8;
typedef __attribute__((ext_vector_type(4))) float f32x4;

__device__ inline short f2bf(float f) {
    union { __hip_bfloat16 h; short s; } u;
    u.h = __float2bfloat16(f);
    return u.s;
}
__device__ inline float bf2f(unsigned short s) {
    union { unsigned u; float f; } x;
    x.u = ((unsigned)s) << 16;
    return x.f;
}
__device__ inline bf16x8 pack8(float4 a, float4 b) {
    bf16x8 r;
    r[0] = f2bf(a.x); r[1] = f2bf(a.y); r[2] = f2bf(a.z); r[3] = f2bf(a.w);
    r[4] = f2bf(b.x); r[5] = f2bf(b.y); r[6] = f2bf(b.z); r[7] = f2bf(b.w);
    return r;
}
__device__ inline bf16x8 pack8s(float4 a, float4 b, float s) {
    bf16x8 r;
    r[0] = f2bf(a.x * s); r[1] = f2bf(a.y * s); r[2] = f2bf(a.z * s); r[3] = f2bf(a.w * s);
    r[4] = f2bf(b.x * s); r[5] = f2bf(b.y * s); r[6] = f2bf(b.z * s); r[7] = f2bf(b.w * s);
    return r;
}

// ---------------- pre-pass: K -> bf16 row-major, V -> V^T bf16 (both plain)
__global__ __launch_bounds__(256) void preconvert_kernel(
    const float* __restrict__ K, const float* __restrict__ V,
    short* __restrict__ Kws, short* __restrict__ VTws)
{
    const int b  = blockIdx.x >> 4;      // NPANEL=16
    const int p  = blockIdx.x & 15;
    const int j0 = p * PANEL;
    const int tid = threadIdx.x;
    const float* Kb = K + ((size_t)b * SLEN + j0) * DIM;
    const float* Vb = V + ((size_t)b * SLEN + j0) * DIM;
    short* Kwb  = Kws  + ((size_t)b * SLEN + j0) * DIM;
    short* VTwb = VTws + (size_t)b * DIM * SLEN;

    #pragma unroll
    for (int it = 0; it < 8; it++) {           // K: 128 rows x 16 float4
        const int idx = it * 256 + tid;
        const int row = idx >> 4, c4 = idx & 15;
        float4 kv = *(const float4*)(Kb + (size_t)row * DIM + c4 * 4);
        *(short4*)(Kwb + (size_t)row * DIM + c4 * 4) =
            make_short4(f2bf(kv.x), f2bf(kv.y), f2bf(kv.z), f2bf(kv.w));
    }
    #pragma unroll
    for (int it = 0; it < 2; it++) {           // V: 4k x 4d register transpose
        const int task = it * 256 + tid;
        const int k4 = task >> 4, d4 = (task & 15) * 4;
        const int kb = k4 * 4;
        const float* vp = Vb + (size_t)kb * DIM + d4;
        float4 r0 = *(const float4*)(vp);
        float4 r1 = *(const float4*)(vp + DIM);
        float4 r2 = *(const float4*)(vp + 2 * DIM);
        float4 r3 = *(const float4*)(vp + 3 * DIM);
        *(short4*)(VTwb + (size_t)(d4 + 0) * SLEN + j0 + kb) =
            make_short4(f2bf(r0.x), f2bf(r1.x), f2bf(r2.x), f2bf(r3.x));
        *(short4*)(VTwb + (size_t)(d4 + 1) * SLEN + j0 + kb) =
            make_short4(f2bf(r0.y), f2bf(r1.y), f2bf(r2.y), f2bf(r3.y));
        *(short4*)(VTwb + (size_t)(d4 + 2) * SLEN + j0 + kb) =
            make_short4(f2bf(r0.z), f2bf(r1.z), f2bf(r2.z), f2bf(r3.z));
        *(short4*)(VTwb + (size_t)(d4 + 3) * SLEN + j0 + kb) =
            make_short4(f2bf(r0.w), f2bf(r1.w), f2bf(r2.w), f2bf(r3.w));
    }
}

#define MFMA16(a, bb, cc) __builtin_amdgcn_mfma_f32_16x16x32_bf16((a), (bb), (cc), 0, 0, 0)

__global__ __launch_bounds__(NTHR, 3) void sdpa_kernel(
    const float* __restrict__ Q, const short* __restrict__ Kws,
    const short* __restrict__ VTws, const int* __restrict__ M,
    float* __restrict__ outCtx, float* __restrict__ outAttn)
{
    __shared__ __align__(16) short sP[NW * 16 * PROWP]; // 17 KB per-wave P
    __shared__ short sMaskBf[SLEN];                     // 4 KB bf16 0/1 col mask

    const int tid = threadIdx.x;
    const int w = tid >> 6, l = tid & 63, g = l >> 4, c = l & 15;
    // bijective XCD swizzle (512 % 8 == 0): one batch's 32 blocks -> one XCD,
    // so the batch's 512 KB bf16 K/V ws is L2-resident for all its blocks.
    const int wg = (blockIdx.x & 7) * (NBATCH * (SLEN / TQ) / 8) + (blockIdx.x >> 3);
    const int b  = wg >> 5;                  // 32 blocks/batch
    const int i0 = (wg & 31) * TQ;
    const int i0w = i0 + w * 16;

    const short* Kwb  = Kws  + (size_t)b * SLEN * DIM;
    const short* VTwb = VTws + (size_t)b * DIM * SLEN;
    const int*   Mb   = M + b * SLEN;

    // Q A-frags, pre-scaled by 1/sqrt(64)=2^-3 (exact; bit-identical scores)
    bf16x8 qa0, qa1;
    {
        const float* qp = Q + ((size_t)b * SLEN + i0w + c) * DIM + g * 8;
        qa0 = pack8s(*(const float4*)(qp),      *(const float4*)(qp + 4),  0.125f);
        qa1 = pack8s(*(const float4*)(qp + 32), *(const float4*)(qp + 36), 0.125f);
    }

    // mask -> LDS once (bf16 1.0/0.0); the ONLY barrier in the kernel
    #pragma unroll
    for (int i = 0; i < 8; i++) {
        const int idx = i * NTHR + tid;
        sMaskBf[idx] = Mb[idx] ? (short)0 : (short)0x3F80;
    }
    __syncthreads();

    // ---- Pass A: row sums. Direct L2 reads of K, zero barriers. ----
    float rsum[4] = {0.f, 0.f, 0.f, 0.f};
    for (int p = 0; p < NPANEL; p++) {
        const int j0 = p * PANEL;
        #pragma unroll
        for (int jt = 0; jt < 8; jt++) {
            const short* kr = Kwb + (size_t)(j0 + jt * 16 + c) * DIM + g * 8;
            bf16x8 kb0 = *(const bf16x8*)(kr);
            bf16x8 kb1 = *(const bf16x8*)(kr + 32);
            f32x4 acc = {0.f, 0.f, 0.f, 0.f};
            acc = MFMA16(qa0, kb0, acc);
            acc = MFMA16(qa1, kb1, acc);
            const float em = bf2f((unsigned short)sMaskBf[j0 + jt * 16 + c]);
            #pragma unroll
            for (int r = 0; r < 4; r++)
                rsum[r] += __expf(acc[r]) * em;
        }
    }
    #pragma unroll
    for (int off = 1; off < 16; off <<= 1) {
        #pragma unroll
        for (int r = 0; r < 4; r++)
            rsum[r] += __shfl_xor(rsum[r], off, 64);
    }
    float scv[4];
    #pragma unroll
    for (int r = 0; r < 4; r++) {
        const bool rm = sMaskBf[i0w + g * 4 + r] == 0;   // row masked?
        scv[r] = (rm || rsum[r] <= 0.f) ? 0.f : 1.f / rsum[r];
    }

    // ---- Pass B: recompute, stage P per-wave, write attn, accumulate PV ----
    short* sPw = sP + w * 16 * PROWP;
    f32x4 pv[4];
    #pragma unroll
    for (int nt = 0; nt < 4; nt++) pv[nt] = (f32x4){0.f, 0.f, 0.f, 0.f};

    for (int p = 0; p < NPANEL; p++) {
        const int j0 = p * PANEL;
        // QK -> normalized P (bf16) in per-wave LDS panel (lgkmcnt-ordered)
        #pragma unroll
        for (int jt = 0; jt < 8; jt++) {
            const short* kr = Kwb + (size_t)(j0 + jt * 16 + c) * DIM + g * 8;
            bf16x8 kb0 = *(const bf16x8*)(kr);
            bf16x8 kb1 = *(const bf16x8*)(kr + 32);
            f32x4 acc = {0.f, 0.f, 0.f, 0.f};
            acc = MFMA16(qa0, kb0, acc);
            acc = MFMA16(qa1, kb1, acc);
            const float em = bf2f((unsigned short)sMaskBf[j0 + jt * 16 + c]);
            #pragma unroll
            for (int r = 0; r < 4; r++)
                sPw[(g * 4 + r) * PROWP + jt * 16 + c] =
                    f2bf(__expf(acc[r]) * em * scv[r]);
        }
        // PV: A-frag b128 from own P panel; B-frag 16B direct L2 read of V^T
        #pragma unroll
        for (int ks = 0; ks < 4; ks++) {
            bf16x8 af = *(const bf16x8*)(sPw + c * PROWP + ks * 32 + g * 8);
            #pragma unroll
            for (int nt = 0; nt < 4; nt++) {
                bf16x8 bfrag = *(const bf16x8*)(VTwb +
                    (size_t)(nt * 16 + c) * SLEN + j0 + ks * 32 + g * 8);
                pv[nt] = MFMA16(af, bfrag, pv[nt]);
            }
        }
        // attn write: 16 rows x 32 float4, fully coalesced, nontemporal
        const size_t rowBase = (size_t)b * SLEN + i0w;
        #pragma unroll
        for (int it = 0; it < 8; it++) {
            const int idx = it * 64 + l;
            const int row = idx >> 5, col4 = idx & 31;
            const unsigned short* pp = (const unsigned short*)sPw + row * PROWP + col4 * 4;
            ushort4 p4 = *(const ushort4*)(pp);
            f32x4 o = {bf2f(p4.x), bf2f(p4.y), bf2f(p4.z), bf2f(p4.w)};
            __builtin_nontemporal_store(o, (f32x4*)(outAttn + (rowBase + row) * SLEN + j0 + col4 * 4));
        }
        // no barrier: sPw is wave-private; next panel's writes are ordered by
        // the compiler's lgkmcnt/program-order within the wave.
    }

    // ctx write: C-layout direct store (pre-normalized P => no further scale)
    #pragma unroll
    for (int nt = 0; nt < 4; nt++) {
        #pragma unroll
        for (int r = 0; r < 4; r++)
            __builtin_nontemporal_store(pv[nt][r],
                outCtx + ((size_t)b * SLEN + i0w + g * 4 + r) * DIM + nt * 16 + c);
    }
}

// ---------------- fallback: verified R4 kernel (used if ws too small) -----
__global__ __launch_bounds__(NTHR, 3) void sdpa_kernel_fb(
    const float* __restrict__ Q, const float* __restrict__ K,
    const float* __restrict__ V, const int* __restrict__ M,
    float* __restrict__ outCtx, float* __restrict__ outAttn)
{
    __shared__ __align__(16) short sK[128 * PROWK];
    __shared__ __align__(16) short sVT[64 * PROWV];
    __shared__ __align__(16) short sP[NW * 16 * PROWP];
    __shared__ float sMask[PANEL];

    const int tid = threadIdx.x;
    const int w = tid >> 6, l = tid & 63, g = l >> 4, c = l & 15;
    const int b  = blockIdx.x >> 5;
    const int i0 = (blockIdx.x & 31) * TQ;
    const int i0w = i0 + w * 16;

    const float* Kb = K + (size_t)b * SLEN * DIM;
    const float* Vb = V + (size_t)b * SLEN * DIM;
    const int*   Mb = M + b * SLEN;

    bf16x8 qa0, qa1;
    {
        const float* qp = Q + ((size_t)b * SLEN + i0w + c) * DIM + g * 8;
        qa0 = pack8(*(const float4*)(qp),      *(const float4*)(qp + 4));
        qa1 = pack8(*(const float4*)(qp + 32), *(const float4*)(qp + 36));
    }

    const float scl = 0.125f;
    float rsum[4] = {0.f, 0.f, 0.f, 0.f};

    for (int p = 0; p < NPANEL; p++) {
        const int j0 = p * PANEL;
        #pragma unroll
        for (int it = 0; it < 8; it++) {
            const int idx = it * NTHR + tid;
            const int row = idx >> 4, c4 = idx & 15;
            float4 kv = *(const float4*)(Kb + (size_t)(j0 + row) * DIM + c4 * 4);
            *(short4*)(sK + row * PROWK + c4 * 4) =
                make_short4(f2bf(kv.x), f2bf(kv.y), f2bf(kv.z), f2bf(kv.w));
        }
        if (tid < PANEL) sMask[tid] = Mb[j0 + tid] ? 0.f : 1.f;
        __syncthreads();
        #pragma unroll
        for (int jt = 0; jt < 8; jt++) {
            const short* kr = sK + (jt * 16 + c) * PROWK + g * 8;
            bf16x8 kb0 = *(const bf16x8*)(kr);
            bf16x8 kb1 = *(const bf16x8*)(kr + 32);
            f32x4 acc = {0.f, 0.f, 0.f, 0.f};
            acc = MFMA16(qa0, kb0, acc);
            acc = MFMA16(qa1, kb1, acc);
            const float em = sMask[jt * 16 + c];
            #pragma unroll
            for (int r = 0; r < 4; r++)
                rsum[r] += __expf(acc[r] * scl) * em;
        }
        __syncthreads();
    }
    #pragma unroll
    for (int off = 1; off < 16; off <<= 1) {
        #pragma unroll
        for (int r = 0; r < 4; r++)
            rsum[r] += __shfl_xor(rsum[r], off, 64);
    }
    float scv[4];
    #pragma unroll
    for (int r = 0; r < 4; r++) {
        const int rm = Mb[i0w + g * 4 + r];
        scv[r] = (rm || rsum[r] <= 0.f) ? 0.f : 1.f / rsum[r];
    }

    short* sPw = sP + w * 16 * PROWP;
    f32x4 pv[4];
    #pragma unroll
    for (int nt = 0; nt < 4; nt++) pv[nt] = (f32x4){0.f, 0.f, 0.f, 0.f};

    for (int p = 0; p < NPANEL; p++) {
        const int j0 = p * PANEL;
        #pragma unroll
        for (int it = 0; it < 8; it++) {
            const int idx = it * NTHR + tid;
            const int row = idx >> 4, c4 = idx & 15;
            float4 kv = *(const float4*)(Kb + (size_t)(j0 + row) * DIM + c4 * 4);
            *(short4*)(sK + row * PROWK + c4 * 4) =
                make_short4(f2bf(kv.x), f2bf(kv.y), f2bf(kv.z), f2bf(kv.w));
        }
        #pragma unroll
        for (int it = 0; it < 2; it++) {
            const int task = it * NTHR + tid;
            const int k4 = task >> 4, d4g = task & 15;
            const int kb = k4 * 4, d4 = d4g * 4;
            const int colb = kb ^ ((d4g & 3) << 3);
            const float* vp = Vb + (size_t)(j0 + kb) * DIM + d4;
            float4 r0 = *(const float4*)(vp);
            float4 r1 = *(const float4*)(vp + DIM);
            float4 r2 = *(const float4*)(vp + 2 * DIM);
            float4 r3 = *(const float4*)(vp + 3 * DIM);
            *(short4*)(sVT + (d4 + 0) * PROWV + colb) =
                make_short4(f2bf(r0.x), f2bf(r1.x), f2bf(r2.x), f2bf(r3.x));
            *(short4*)(sVT + (d4 + 1) * PROWV + colb) =
                make_short4(f2bf(r0.y), f2bf(r1.y), f2bf(r2.y), f2bf(r3.y));
            *(short4*)(sVT + (d4 + 2) * PROWV + colb) =
                make_short4(f2bf(r0.z), f2bf(r1.z), f2bf(r2.z), f2bf(r3.z));
            *(short4*)(sVT + (d4 + 3) * PROWV + colb) =
                make_short4(f2bf(r0.w), f2bf(r1.w), f2bf(r2.w), f2bf(r3.w));
        }
        if (tid < PANEL) sMask[tid] = Mb[j0 + tid] ? 0.f : 1.f;
        __syncthreads();

        #pragma unroll
        for (int jt = 0; jt < 8; jt++) {
            const short* kr = sK + (jt * 16 + c) * PROWK + g * 8;
            bf16x8 kb0 = *(const bf16x8*)(kr);
            bf16x8 kb1 = *(const bf16x8*)(kr + 32);
            f32x4 acc = {0.f, 0.f, 0.f, 0.f};
            acc = MFMA16(qa0, kb0, acc);
            acc = MFMA16(qa1, kb1, acc);
            const float em = sMask[jt * 16 + c];
            #pragma unroll
            for (int r = 0; r < 4; r++)
                sPw[(g * 4 + r) * PROWP + jt * 16 + c] =
                    f2bf(__expf(acc[r] * scl) * em * scv[r]);
        }
        #pragma unroll
        for (int ks = 0; ks < 4; ks++) {
            bf16x8 af = *(const bf16x8*)(sPw + c * PROWP + ks * 32 + g * 8);
            #pragma unroll
            for (int nt = 0; nt < 4; nt++) {
                const int d = nt * 16 + c;
                const int gp = g ^ ((d >> 2) & 3);
                bf16x8 bfrag = *(const bf16x8*)(sVT + d * PROWV + ks * 32 + gp * 8);
                pv[nt] = MFMA16(af, bfrag, pv[nt]);
            }
        }
        const size_t rowBase = (size_t)b * SLEN + i0w;
        #pragma unroll
        for (int it = 0; it < 8; it++) {
            const int idx = it * 64 + l;
            const int row = idx >> 5, col4 = idx & 31;
            const unsigned short* pp = (const unsigned short*)sPw + row * PROWP + col4 * 4;
            ushort4 p4 = *(const ushort4*)(pp);
            float4 o = {bf2f(p4.x), bf2f(p4.y), bf2f(p4.z), bf2f(p4.w)};
            *(float4*)(outAttn + (rowBase + row) * SLEN + j0 + col4 * 4) = o;
        }
        __syncthreads();
    }

    #pragma unroll
    for (int nt = 0; nt < 4; nt++) {
        #pragma unroll
        for (int r = 0; r < 4; r++)
            outCtx[((size_t)b * SLEN + i0w + g * 4 + r) * DIM + nt * 16 + c] = pv[nt][r];
    }
}

extern "C" void kernel_launch(void* const* d_in, const int* in_sizes, int n_in,
                              void* d_out, int out_size, void* d_ws, size_t ws_size,
                              hipStream_t stream) {
    const float* Q = (const float*)d_in[0];
    const float* K = (const float*)d_in[1];
    const float* V = (const float*)d_in[2];
    const int*   M = (const int*)d_in[3];
    float* outCtx  = (float*)d_out;
    float* outAttn = (float*)d_out + (size_t)NBATCH * SLEN * DIM;
    dim3 grid(NBATCH * (SLEN / TQ));   // 512 blocks

    const size_t nElem = (size_t)NBATCH * SLEN * DIM;      // 2,097,152
    const size_t wsNeed = nElem * 2 * sizeof(short);       // 8 MB
    if (d_ws != nullptr && ws_size >= wsNeed) {
        short* Kws  = (short*)d_ws;
        short* VTws = Kws + nElem;
        preconvert_kernel<<<dim3(NBATCH * NPANEL), 256, 0, stream>>>(K, V, Kws, VTws);
        sdpa_kernel<<<grid, NTHR, 0, stream>>>(Q, Kws, VTws, M, outCtx, outAttn);
    } else {
        sdpa_kernel_fb<<<grid, NTHR, 0, stream>>>(Q, K, V, M, outCtx, outAttn);
    }
}

// Round 6
// 329.185 us; speedup vs baseline: 1.3055x; 1.3055x over previous
//
#include <hip/hip_runtime.h>
#include <hip/hip_bf16.h>

// B=16, S=2048, D=64 attention w/ symmetric pad mask.
// out = [context (B*S*D fp32), attn (B*S*S fp32)] concatenated.
//
// R10: fix R9's latency-boundedness (197us kernel, VALU 12% / MFMA 5% /
// occupancy 23% -> everything idle, waiting on L2).
//  1. Grid was the occupancy cap all along: 512 blocks = 2 blocks/CU. Now
//     TQ=32 -> 1024 blocks = 4 blocks/CU, 4 waves/block SPLIT-K (wave (h,kh)
//     does 16 q-rows x 1024 k-cols) -> 16 waves/CU, half the chain per wave.
//     rsum and PV partials combined via tiny LDS exchanges; 3 barriers total.
//  2. Wave-order PACKED operands: pre-pass emits K and V^T in exactly the
//     lane order the wave consumes -> every frag load is base + lane*16B,
//     a dense coalesced 1KB wave-load (R9's was 16 scattered 64B segments).
//     Values bit-identical; only the address mapping changed.
//  3. Explicit depth-2 software prefetch (named regs, static indexing) on
//     the K-frag stream and V-frag stream (R9: VGPR=52, ~no loads in flight).
// Kept: XCD swizzle (1024%8==0; 2 batches' 1MB ws per XCD L2), bf16 LDS mask
// (lgkmcnt path), NT attn/ctx stores, Q pre-scaled by 1/8. Fallback R4 kernel.
#define NBATCH 16
#define SLEN   2048
#define DIM    64
#define TQ     32
#define NTHR   256
#define NW     4
#define PANEL  128
#define NPANEL (SLEN / PANEL)   // 16
#define PROWP  136              // shorts: 128 data + 8 pad
// fallback (R4) layout constants
#define TQFB   64
#define PROWK  72
#define PROWV  136

typedef __attribute__((ext_vector_type(8))) short bf16x8;
typedef __attribute__((ext_vector_type(4))) float f32x4;

__device__ inline short f2bf(float f) {
    union { __hip_bfloat16 h; short s; } u;
    u.h = __float2bfloat16(f);
    return u.s;
}
__device__ inline float bf2f(unsigned short s) {
    union { unsigned u; float f; } x;
    x.u = ((unsigned)s) << 16;
    return x.f;
}
__device__ inline bf16x8 pack8(float4 a, float4 b) {
    bf16x8 r;
    r[0] = f2bf(a.x); r[1] = f2bf(a.y); r[2] = f2bf(a.z); r[3] = f2bf(a.w);
    r[4] = f2bf(b.x); r[5] = f2bf(b.y); r[6] = f2bf(b.z); r[7] = f2bf(b.w);
    return r;
}
__device__ inline bf16x8 pack8s(float4 a, float4 b, float s) {
    bf16x8 r;
    r[0] = f2bf(a.x * s); r[1] = f2bf(a.y * s); r[2] = f2bf(a.z * s); r[3] = f2bf(a.w * s);
    r[4] = f2bf(b.x * s); r[5] = f2bf(b.y * s); r[6] = f2bf(b.z * s); r[7] = f2bf(b.w * s);
    return r;
}

// ---------------- pre-pass: wave-order packed K and V^T -------------------
// Kp per batch: [trow 0..127][half 0..1][lane 0..63][8 shorts]
//   lane(g,c) half h elem e  <->  K[trow*16 + c][h*32 + g*8 + e]
// Vp per batch: [panel 0..15][i=ks*4+nt 0..15][lane 0..63][8 shorts]
//   lane(g,c) elem e  <->  V[p*128 + ks*32 + g*8 + e][nt*16 + c]   (V^T frag)
__global__ __launch_bounds__(256) void preconvert_kernel(
    const float* __restrict__ K, const float* __restrict__ V,
    short* __restrict__ Kp, short* __restrict__ Vp)
{
    const int b  = blockIdx.x >> 4;      // NPANEL=16
    const int p  = blockIdx.x & 15;
    const int j0 = p * PANEL;
    const int tid = threadIdx.x;
    const float* Kb = K + ((size_t)b * SLEN + j0) * DIM;
    const float* Vb = V + ((size_t)b * SLEN + j0) * DIM;
    short* Kpb = Kp + (size_t)b * SLEN * DIM + (size_t)(j0 >> 4) * 1024;
    short* Vpb = Vp + (size_t)b * SLEN * DIM + (size_t)p * 8192;

    #pragma unroll
    for (int it = 0; it < 4; it++) {           // K: 1024 lane-slots
        const int s = it * 256 + tid;
        const int trl = s >> 7, half = (s >> 6) & 1, lane = s & 63;
        const int g = lane >> 4, cc = lane & 15;
        const float* src = Kb + (size_t)(trl * 16 + cc) * DIM + half * 32 + g * 8;
        *(bf16x8*)(Kpb + (size_t)trl * 1024 + half * 512 + lane * 8) =
            pack8(*(const float4*)(src), *(const float4*)(src + 4));
    }
    #pragma unroll
    for (int it = 0; it < 2; it++) {           // V: 4k x 4d register transpose
        const int task = it * 256 + tid;
        const int kb = (task >> 4) * 4, d4 = (task & 15) * 4;
        const float* vp = Vb + (size_t)kb * DIM + d4;
        float4 r0 = *(const float4*)(vp);
        float4 r1 = *(const float4*)(vp + DIM);
        float4 r2 = *(const float4*)(vp + 2 * DIM);
        float4 r3 = *(const float4*)(vp + 3 * DIM);
        const int ks = (kb >> 5) & 3, gg = (kb >> 3) & 3, e = kb & 7;
        #define VDST(dd) (Vpb + ((size_t)((ks * 4 + ((d4 + dd) >> 4)) * 64 \
                              + gg * 16 + ((d4 + dd) & 15))) * 8 + e)
        *(short4*)VDST(0) = make_short4(f2bf(r0.x), f2bf(r1.x), f2bf(r2.x), f2bf(r3.x));
        *(short4*)VDST(1) = make_short4(f2bf(r0.y), f2bf(r1.y), f2bf(r2.y), f2bf(r3.y));
        *(short4*)VDST(2) = make_short4(f2bf(r0.z), f2bf(r1.z), f2bf(r2.z), f2bf(r3.z));
        *(short4*)VDST(3) = make_short4(f2bf(r0.w), f2bf(r1.w), f2bf(r2.w), f2bf(r3.w));
        #undef VDST
    }
}

#define MFMA16(a, bb, cc) __builtin_amdgcn_mfma_f32_16x16x32_bf16((a), (bb), (cc), 0, 0, 0)

__global__ __launch_bounds__(NTHR, 4) void sdpa_kernel(
    const float* __restrict__ Q, const short* __restrict__ Kp,
    const short* __restrict__ Vp, const int* __restrict__ M,
    float* __restrict__ outCtx, float* __restrict__ outAttn)
{
    __shared__ __align__(16) short sP[NW * 16 * PROWP]; // 17 KB per-wave P
    __shared__ short sMaskBf[SLEN];                     // 4 KB bf16 0/1 col mask
    __shared__ float sRsum[NW * 16];                    // 256 B partial rowsums

    const int tid = threadIdx.x;
    const int w = tid >> 6, l = tid & 63, g = l >> 4, c = l & 15;
    const int h = w & 1, kh = w >> 1;        // q-row half / K half
    // bijective XCD swizzle: 1024 % 8 == 0. 128 consecutive wg per XCD =
    // 2 batches -> their 1 MB packed K/V ws is L2-resident per XCD.
    const int wg = (blockIdx.x & 7) * 128 + (blockIdx.x >> 3);
    const int b  = wg >> 6;                  // 64 blocks/batch
    const int i0 = (wg & 63) * TQ;
    const int i0w = i0 + h * 16;             // this wave's 16 q-rows

    const short* Kwb = Kp + (size_t)b * SLEN * DIM;
    const short* Vwb = Vp + (size_t)b * SLEN * DIM;
    const int*   Mb  = M + b * SLEN;

    // Q A-frags, pre-scaled by 1/sqrt(64)=2^-3 (exact; bit-identical scores)
    bf16x8 qa0, qa1;
    {
        const float* qp = Q + ((size_t)b * SLEN + i0w + c) * DIM + g * 8;
        qa0 = pack8s(*(const float4*)(qp),      *(const float4*)(qp + 4),  0.125f);
        qa1 = pack8s(*(const float4*)(qp + 32), *(const float4*)(qp + 36), 0.125f);
    }

    // mask -> LDS once (bf16 1.0/0.0)
    #pragma unroll
    for (int i = 0; i < 8; i++) {
        const int idx = i * NTHR + tid;
        sMaskBf[idx] = Mb[idx] ? (short)0 : (short)0x3F80;
    }
    __syncthreads();                                    // B1

    const int tbase = kh * 64;                          // 64 row-groups per K-half
    // ---- Pass A: partial row sums over this wave's K-half, depth-2 prefetch
    float rsum[4] = {0.f, 0.f, 0.f, 0.f};
    {
        const short* a0 = Kwb + (size_t)(tbase + 0) * 1024 + l * 8;
        const short* a1 = Kwb + (size_t)(tbase + 1) * 1024 + l * 8;
        bf16x8 p0a = *(const bf16x8*)(a0), p0b = *(const bf16x8*)(a0 + 512);
        bf16x8 p1a = *(const bf16x8*)(a1), p1b = *(const bf16x8*)(a1 + 512);
        #pragma unroll 4
        for (int t = 0; t < 64; t++) {
            bf16x8 ca = p0a, cb = p0b;
            p0a = p1a; p0b = p1b;
            if (t + 2 < 64) {
                const short* an = Kwb + (size_t)(tbase + t + 2) * 1024 + l * 8;
                p1a = *(const bf16x8*)(an); p1b = *(const bf16x8*)(an + 512);
            }
            f32x4 acc = {0.f, 0.f, 0.f, 0.f};
            acc = MFMA16(qa0, ca, acc);
            acc = MFMA16(qa1, cb, acc);
            const float em = bf2f((unsigned short)sMaskBf[kh * 1024 + t * 16 + c]);
            #pragma unroll
            for (int r = 0; r < 4; r++)
                rsum[r] += __expf(acc[r]) * em;
        }
    }
    #pragma unroll
    for (int off = 1; off < 16; off <<= 1) {
        #pragma unroll
        for (int r = 0; r < 4; r++)
            rsum[r] += __shfl_xor(rsum[r], off, 64);
    }
    if (c == 0) {
        #pragma unroll
        for (int r = 0; r < 4; r++)
            sRsum[w * 16 + g * 4 + r] = rsum[r];
    }
    __syncthreads();                                    // B2
    float scv[4];
    #pragma unroll
    for (int r = 0; r < 4; r++) {
        const float tot = rsum[r] + sRsum[(w ^ 2) * 16 + g * 4 + r];
        const bool rm = sMaskBf[i0w + g * 4 + r] == 0;  // row masked?
        scv[r] = (rm || tot <= 0.f) ? 0.f : 1.f / tot;
    }

    // ---- Pass B: recompute P, write attn, accumulate PV partials ----
    short* sPw = sP + w * 16 * PROWP;
    f32x4 pv[4];
    #pragma unroll
    for (int nt = 0; nt < 4; nt++) pv[nt] = (f32x4){0.f, 0.f, 0.f, 0.f};

    bf16x8 p0a, p0b, p1a, p1b;
    {
        const short* a0 = Kwb + (size_t)(tbase + 0) * 1024 + l * 8;
        const short* a1 = Kwb + (size_t)(tbase + 1) * 1024 + l * 8;
        p0a = *(const bf16x8*)(a0); p0b = *(const bf16x8*)(a0 + 512);
        p1a = *(const bf16x8*)(a1); p1b = *(const bf16x8*)(a1 + 512);
    }
    for (int p = 0; p < 8; p++) {
        // QK -> normalized P (bf16) in per-wave LDS panel
        #pragma unroll
        for (int jt = 0; jt < 8; jt++) {
            const int tt = p * 8 + jt;
            bf16x8 ca = p0a, cb = p0b;
            p0a = p1a; p0b = p1b;
            if (tt + 2 < 64) {
                const short* an = Kwb + (size_t)(tbase + tt + 2) * 1024 + l * 8;
                p1a = *(const bf16x8*)(an); p1b = *(const bf16x8*)(an + 512);
            }
            f32x4 acc = {0.f, 0.f, 0.f, 0.f};
            acc = MFMA16(qa0, ca, acc);
            acc = MFMA16(qa1, cb, acc);
            const float em = bf2f((unsigned short)sMaskBf[kh * 1024 + tt * 16 + c]);
            #pragma unroll
            for (int r = 0; r < 4; r++)
                sPw[(g * 4 + r) * PROWP + jt * 16 + c] =
                    f2bf(__expf(acc[r]) * em * scv[r]);
        }
        // PV: A-frag b128 from own P panel; B-frag dense packed load, depth-2
        {
            const short* vb = Vwb + (size_t)(kh * 8 + p) * 8192 + l * 8;
            bf16x8 v0 = *(const bf16x8*)(vb);
            bf16x8 v1 = *(const bf16x8*)(vb + 512);
            bf16x8 af;
            #pragma unroll
            for (int i = 0; i < 16; i++) {
                bf16x8 cur = v0;
                v0 = v1;
                if (i + 2 < 16) v1 = *(const bf16x8*)(vb + (i + 2) * 512);
                if ((i & 3) == 0)
                    af = *(const bf16x8*)(sPw + c * PROWP + (i >> 2) * 32 + g * 8);
                pv[i & 3] = MFMA16(af, cur, pv[i & 3]);
            }
        }
        // attn write: 16 rows x 32 float4, coalesced, nontemporal
        const size_t rowBase = (size_t)b * SLEN + i0w;
        const int colb = kh * 1024 + p * PANEL;
        #pragma unroll
        for (int it = 0; it < 8; it++) {
            const int idx = it * 64 + l;
            const int row = idx >> 5, col4 = idx & 31;
            const unsigned short* pp = (const unsigned short*)sPw + row * PROWP + col4 * 4;
            ushort4 p4 = *(const ushort4*)(pp);
            f32x4 o = {bf2f(p4.x), bf2f(p4.y), bf2f(p4.z), bf2f(p4.w)};
            __builtin_nontemporal_store(o,
                (f32x4*)(outAttn + (rowBase + row) * SLEN + colb + col4 * 4));
        }
    }

    // ---- PV combine across K-halves, then ctx write ----
    if (kh == 1) {
        float* fb = (float*)sPw;            // reuse own P region (4 KB as f32)
        #pragma unroll
        for (int nt = 0; nt < 4; nt++)
            #pragma unroll
            for (int r = 0; r < 4; r++)
                fb[(g * 4 + r) * 64 + nt * 16 + c] = pv[nt][r];
    }
    __syncthreads();                                    // B3
    if (kh == 0) {
        const float* fb = (const float*)(sP + (w + 2) * 16 * PROWP);
        #pragma unroll
        for (int nt = 0; nt < 4; nt++)
            #pragma unroll
            for (int r = 0; r < 4; r++) {
                const float v = pv[nt][r] + fb[(g * 4 + r) * 64 + nt * 16 + c];
                __builtin_nontemporal_store(v,
                    outCtx + ((size_t)b * SLEN + i0w + g * 4 + r) * DIM + nt * 16 + c);
            }
    }
}

// ---------------- fallback: verified R4 kernel (used if ws too small) -----
__global__ __launch_bounds__(NTHR, 3) void sdpa_kernel_fb(
    const float* __restrict__ Q, const float* __restrict__ K,
    const float* __restrict__ V, const int* __restrict__ M,
    float* __restrict__ outCtx, float* __restrict__ outAttn)
{
    __shared__ __align__(16) short sK[128 * PROWK];
    __shared__ __align__(16) short sVT[64 * PROWV];
    __shared__ __align__(16) short sP[NW * 16 * PROWP];
    __shared__ float sMask[PANEL];

    const int tid = threadIdx.x;
    const int w = tid >> 6, l = tid & 63, g = l >> 4, c = l & 15;
    const int b  = blockIdx.x >> 5;
    const int i0 = (blockIdx.x & 31) * TQFB;
    const int i0w = i0 + w * 16;

    const float* Kb = K + (size_t)b * SLEN * DIM;
    const float* Vb = V + (size_t)b * SLEN * DIM;
    const int*   Mb = M + b * SLEN;

    bf16x8 qa0, qa1;
    {
        const float* qp = Q + ((size_t)b * SLEN + i0w + c) * DIM + g * 8;
        qa0 = pack8(*(const float4*)(qp),      *(const float4*)(qp + 4));
        qa1 = pack8(*(const float4*)(qp + 32), *(const float4*)(qp + 36));
    }

    const float scl = 0.125f;
    float rsum[4] = {0.f, 0.f, 0.f, 0.f};

    for (int p = 0; p < NPANEL; p++) {
        const int j0 = p * PANEL;
        #pragma unroll
        for (int it = 0; it < 8; it++) {
            const int idx = it * NTHR + tid;
            const int row = idx >> 4, c4 = idx & 15;
            float4 kv = *(const float4*)(Kb + (size_t)(j0 + row) * DIM + c4 * 4);
            *(short4*)(sK + row * PROWK + c4 * 4) =
                make_short4(f2bf(kv.x), f2bf(kv.y), f2bf(kv.z), f2bf(kv.w));
        }
        if (tid < PANEL) sMask[tid] = Mb[j0 + tid] ? 0.f : 1.f;
        __syncthreads();
        #pragma unroll
        for (int jt = 0; jt < 8; jt++) {
            const short* kr = sK + (jt * 16 + c) * PROWK + g * 8;
            bf16x8 kb0 = *(const bf16x8*)(kr);
            bf16x8 kb1 = *(const bf16x8*)(kr + 32);
            f32x4 acc = {0.f, 0.f, 0.f, 0.f};
            acc = MFMA16(qa0, kb0, acc);
            acc = MFMA16(qa1, kb1, acc);
            const float em = sMask[jt * 16 + c];
            #pragma unroll
            for (int r = 0; r < 4; r++)
                rsum[r] += __expf(acc[r] * scl) * em;
        }
        __syncthreads();
    }
    #pragma unroll
    for (int off = 1; off < 16; off <<= 1) {
        #pragma unroll
        for (int r = 0; r < 4; r++)
            rsum[r] += __shfl_xor(rsum[r], off, 64);
    }
    float scv[4];
    #pragma unroll
    for (int r = 0; r < 4; r++) {
        const int rm = Mb[i0w + g * 4 + r];
        scv[r] = (rm || rsum[r] <= 0.f) ? 0.f : 1.f / rsum[r];
    }

    short* sPw = sP + w * 16 * PROWP;
    f32x4 pv[4];
    #pragma unroll
    for (int nt = 0; nt < 4; nt++) pv[nt] = (f32x4){0.f, 0.f, 0.f, 0.f};

    for (int p = 0; p < NPANEL; p++) {
        const int j0 = p * PANEL;
        #pragma unroll
        for (int it = 0; it < 8; it++) {
            const int idx = it * NTHR + tid;
            const int row = idx >> 4, c4 = idx & 15;
            float4 kv = *(const float4*)(Kb + (size_t)(j0 + row) * DIM + c4 * 4);
            *(short4*)(sK + row * PROWK + c4 * 4) =
                make_short4(f2bf(kv.x), f2bf(kv.y), f2bf(kv.z), f2bf(kv.w));
        }
        #pragma unroll
        for (int it = 0; it < 2; it++) {
            const int task = it * NTHR + tid;
            const int k4 = task >> 4, d4g = task & 15;
            const int kb = k4 * 4, d4 = d4g * 4;
            const int colb = kb ^ ((d4g & 3) << 3);
            const float* vp = Vb + (size_t)(j0 + kb) * DIM + d4;
            float4 r0 = *(const float4*)(vp);
            float4 r1 = *(const float4*)(vp + DIM);
            float4 r2 = *(const float4*)(vp + 2 * DIM);
            float4 r3 = *(const float4*)(vp + 3 * DIM);
            *(short4*)(sVT + (d4 + 0) * PROWV + colb) =
                make_short4(f2bf(r0.x), f2bf(r1.x), f2bf(r2.x), f2bf(r3.x));
            *(short4*)(sVT + (d4 + 1) * PROWV + colb) =
                make_short4(f2bf(r0.y), f2bf(r1.y), f2bf(r2.y), f2bf(r3.y));
            *(short4*)(sVT + (d4 + 2) * PROWV + colb) =
                make_short4(f2bf(r0.z), f2bf(r1.z), f2bf(r2.z), f2bf(r3.z));
            *(short4*)(sVT + (d4 + 3) * PROWV + colb) =
                make_short4(f2bf(r0.w), f2bf(r1.w), f2bf(r2.w), f2bf(r3.w));
        }
        if (tid < PANEL) sMask[tid] = Mb[j0 + tid] ? 0.f : 1.f;
        __syncthreads();

        #pragma unroll
        for (int jt = 0; jt < 8; jt++) {
            const short* kr = sK + (jt * 16 + c) * PROWK + g * 8;
            bf16x8 kb0 = *(const bf16x8*)(kr);
            bf16x8 kb1 = *(const bf16x8*)(kr + 32);
            f32x4 acc = {0.f, 0.f, 0.f, 0.f};
            acc = MFMA16(qa0, kb0, acc);
            acc = MFMA16(qa1, kb1, acc);
            const float em = sMask[jt * 16 + c];
            #pragma unroll
            for (int r = 0; r < 4; r++)
                sPw[(g * 4 + r) * PROWP + jt * 16 + c] =
                    f2bf(__expf(acc[r] * scl) * em * scv[r]);
        }
        #pragma unroll
        for (int ks = 0; ks < 4; ks++) {
            bf16x8 af = *(const bf16x8*)(sPw + c * PROWP + ks * 32 + g * 8);
            #pragma unroll
            for (int nt = 0; nt < 4; nt++) {
                const int d = nt * 16 + c;
                const int gp = g ^ ((d >> 2) & 3);
                bf16x8 bfrag = *(const bf16x8*)(sVT + d * PROWV + ks * 32 + gp * 8);
                pv[nt] = MFMA16(af, bfrag, pv[nt]);
            }
        }
        const size_t rowBase = (size_t)b * SLEN + i0w;
        #pragma unroll
        for (int it = 0; it < 8; it++) {
            const int idx = it * 64 + l;
            const int row = idx >> 5, col4 = idx & 31;
            const unsigned short* pp = (const unsigned short*)sPw + row * PROWP + col4 * 4;
            ushort4 p4 = *(const ushort4*)(pp);
            float4 o = {bf2f(p4.x), bf2f(p4.y), bf2f(p4.z), bf2f(p4.w)};
            *(float4*)(outAttn + (rowBase + row) * SLEN + j0 + col4 * 4) = o;
        }
        __syncthreads();
    }

    #pragma unroll
    for (int nt = 0; nt < 4; nt++) {
        #pragma unroll
        for (int r = 0; r < 4; r++)
            outCtx[((size_t)b * SLEN + i0w + g * 4 + r) * DIM + nt * 16 + c] = pv[nt][r];
    }
}

extern "C" void kernel_launch(void* const* d_in, const int* in_sizes, int n_in,
                              void* d_out, int out_size, void* d_ws, size_t ws_size,
                              hipStream_t stream) {
    const float* Q = (const float*)d_in[0];
    const float* K = (const float*)d_in[1];
    const float* V = (const float*)d_in[2];
    const int*   M = (const int*)d_in[3];
    float* outCtx  = (float*)d_out;
    float* outAttn = (float*)d_out + (size_t)NBATCH * SLEN * DIM;

    const size_t nElem = (size_t)NBATCH * SLEN * DIM;      // 2,097,152
    const size_t wsNeed = nElem * 2 * sizeof(short);       // 8 MB
    if (d_ws != nullptr && ws_size >= wsNeed) {
        short* Kp = (short*)d_ws;
        short* Vp = Kp + nElem;
        preconvert_kernel<<<dim3(NBATCH * NPANEL), 256, 0, stream>>>(K, V, Kp, Vp);
        sdpa_kernel<<<dim3(NBATCH * (SLEN / TQ)), NTHR, 0, stream>>>(Q, Kp, Vp, M, outCtx, outAttn);
    } else {
        sdpa_kernel_fb<<<dim3(NBATCH * (SLEN / TQFB)), NTHR, 0, stream>>>(Q, K, V, M, outCtx, outAttn);
    }
}

// Round 7
// 311.220 us; speedup vs baseline: 1.3808x; 1.0577x over previous
//
#include <hip/hip_runtime.h>
#include <hip/hip_bf16.h>

// B=16, S=2048, D=64 attention w/ symmetric pad mask.
// out = [context (B*S*D fp32), attn (B*S*S fp32)] concatenated.
//
// R11: minimum-barrier hybrid of the two verified structures.
//  - Kernel-share ledger (overhead ~232us const): R5=82, R8=86, R9=198,
//    R10=97us -> LDS-staged K (gload_lds dbuf) beats L2-direct; R10's packed
//    wave-order V layout is the one asset worth keeping.
//  - Pass B: NO sVT. PV B-frags read direct from L2 in R10's packed Vp
//    layout (dense base+lane*16B, depth-2 named-reg prefetch) -> V off the
//    LDS/barrier path entirely. Freed LDS -> two K buffers -> pass B is a
//    true 2-phase: stage K(p+1)->buf^1 | QK(buf) | PV | attn write | ONE
//    barrier. 17 barriers instead of R8's 32. vmcnt queue order per panel is
//    [stage, V-loads, stores]: V-waits can only force the (needed anyway)
//    stage, never a store drain; stores drain once per panel.
//  - LDS 53 KB -> 3 blocks/CU kept. Pass A = R8's dbuf (1 barrier/panel).
//    bf16 LDS mask (lgkmcnt), XCD swizzle, NT stores, Q prescale: unchanged.
// Fallback R4 kernel retained for ws-too-small.
#define NBATCH 16
#define SLEN   2048
#define DIM    64
#define TQ     64
#define NTHR   256
#define NW     4
#define PANEL  128
#define NPANEL (SLEN / PANEL)   // 16
#define PROWP  136              // shorts: 128 data + 8 pad
// fallback (R4) layout constants
#define PROWK  72
#define PROWV  136

typedef __attribute__((ext_vector_type(8))) short bf16x8;
typedef __attribute__((ext_vector_type(4))) float f32x4;

__device__ inline short f2bf(float f) {
    union { __hip_bfloat16 h; short s; } u;
    u.h = __float2bfloat16(f);
    return u.s;
}
__device__ inline float bf2f(unsigned short s) {
    union { unsigned u; float f; } x;
    x.u = ((unsigned)s) << 16;
    return x.f;
}
__device__ inline bf16x8 pack8(float4 a, float4 b) {
    bf16x8 r;
    r[0] = f2bf(a.x); r[1] = f2bf(a.y); r[2] = f2bf(a.z); r[3] = f2bf(a.w);
    r[4] = f2bf(b.x); r[5] = f2bf(b.y); r[6] = f2bf(b.z); r[7] = f2bf(b.w);
    return r;
}
__device__ inline bf16x8 pack8s(float4 a, float4 b, float s) {
    bf16x8 r;
    r[0] = f2bf(a.x * s); r[1] = f2bf(a.y * s); r[2] = f2bf(a.z * s); r[3] = f2bf(a.w * s);
    r[4] = f2bf(b.x * s); r[5] = f2bf(b.y * s); r[6] = f2bf(b.z * s); r[7] = f2bf(b.w * s);
    return r;
}

// ---------------- pre-pass ------------------------------------------------
// Kws (R8 layout, verified): row j's 8 16B-blocks stored at blk ^ (j&7)
//   -> gload_lds staging lands LDS-bank-spread for the QK ds_read_b128s.
// Vp (R10 layout, verified): per panel p, [i=ks*4+nt 0..15][lane 0..63][8sh]
//   lane(g,c) elem e <-> V[p*128 + ks*32 + g*8 + e][nt*16 + c]  (V^T frag)
__global__ __launch_bounds__(256) void preconvert_kernel(
    const float* __restrict__ K, const float* __restrict__ V,
    short* __restrict__ Kws, short* __restrict__ Vp)
{
    const int b  = blockIdx.x >> 4;      // NPANEL=16
    const int p  = blockIdx.x & 15;
    const int j0 = p * PANEL;
    const int tid = threadIdx.x;
    const float* Kb = K + ((size_t)b * SLEN + j0) * DIM;
    const float* Vb = V + ((size_t)b * SLEN + j0) * DIM;
    short* Kwb = Kws + ((size_t)b * SLEN + j0) * DIM;
    short* Vpb = Vp  + (size_t)b * SLEN * DIM + (size_t)p * 8192;

    #pragma unroll
    for (int it = 0; it < 8; it++) {           // K: 128 rows x 16 float4
        const int idx = it * 256 + tid;
        const int row = idx >> 4, c4 = idx & 15;
        float4 kv = *(const float4*)(Kb + (size_t)row * DIM + c4 * 4);
        const int blk = (c4 >> 1) ^ (row & 7); // natural block c4>>1, swizzled
        *(short4*)(Kwb + (size_t)row * DIM + blk * 8 + (c4 & 1) * 4) =
            make_short4(f2bf(kv.x), f2bf(kv.y), f2bf(kv.z), f2bf(kv.w));
    }
    #pragma unroll
    for (int it = 0; it < 2; it++) {           // V: 4k x 4d register transpose
        const int task = it * 256 + tid;
        const int kb = (task >> 4) * 4, d4 = (task & 15) * 4;
        const float* vp = Vb + (size_t)kb * DIM + d4;
        float4 r0 = *(const float4*)(vp);
        float4 r1 = *(const float4*)(vp + DIM);
        float4 r2 = *(const float4*)(vp + 2 * DIM);
        float4 r3 = *(const float4*)(vp + 3 * DIM);
        const int ks = (kb >> 5) & 3, gg = (kb >> 3) & 3, e = kb & 7;
        #define VDST(dd) (Vpb + ((size_t)((ks * 4 + ((d4 + dd) >> 4)) * 64 \
                              + gg * 16 + ((d4 + dd) & 15))) * 8 + e)
        *(short4*)VDST(0) = make_short4(f2bf(r0.x), f2bf(r1.x), f2bf(r2.x), f2bf(r3.x));
        *(short4*)VDST(1) = make_short4(f2bf(r0.y), f2bf(r1.y), f2bf(r2.y), f2bf(r3.y));
        *(short4*)VDST(2) = make_short4(f2bf(r0.z), f2bf(r1.z), f2bf(r2.z), f2bf(r3.z));
        *(short4*)VDST(3) = make_short4(f2bf(r0.w), f2bf(r1.w), f2bf(r2.w), f2bf(r3.w));
        #undef VDST
    }
}

// ---- async staging: linear LDS copy (swizzle already in global layout) ----
__device__ __forceinline__ void stage_k_panel(const short* __restrict__ Kwb, int j0,
                                              short* sdst, int w, int l) {
    const short* src = Kwb + (size_t)j0 * DIM + w * 512 + l * 8;  // per-lane
    short* dst = sdst + w * 512;                                  // wave-uniform
    #pragma unroll
    for (int i = 0; i < 4; i++)
        __builtin_amdgcn_global_load_lds((const unsigned int*)(src + i * 2048),
                                         (unsigned int*)(dst + i * 2048), 16, 0, 0);
}

#define MFMA16(a, bb, cc) __builtin_amdgcn_mfma_f32_16x16x32_bf16((a), (bb), (cc), 0, 0, 0)

__global__ __launch_bounds__(NTHR, 3) void sdpa_kernel(
    const float* __restrict__ Q, const short* __restrict__ Kws,
    const short* __restrict__ Vp, const int* __restrict__ M,
    float* __restrict__ outCtx, float* __restrict__ outAttn)
{
    __shared__ __align__(16) short sK0[PANEL * DIM];    // 16 KB K buffer 0
    __shared__ __align__(16) short sK1[PANEL * DIM];    // 16 KB K buffer 1
    __shared__ __align__(16) short sP[NW * 16 * PROWP]; // 17 KB per-wave P
    __shared__ short sMaskBf[SLEN];                     // 4 KB bf16 0/1 col mask

    const int tid = threadIdx.x;
    const int w = tid >> 6, l = tid & 63, g = l >> 4, c = l & 15;
    // bijective XCD swizzle: 512 blocks % 8 XCDs == 0 -> simple form.
    const int wg = (blockIdx.x & 7) * (NBATCH * (SLEN / TQ) / 8) + (blockIdx.x >> 3);
    const int b  = wg >> 5;                  // 32 blocks/batch
    const int i0 = (wg & 31) * TQ;
    const int i0w = i0 + w * 16;

    const short* Kwb = Kws + (size_t)b * SLEN * DIM;
    const short* Vwb = Vp  + (size_t)b * SLEN * DIM;
    const int*   Mb  = M + b * SLEN;

    // Q A-frags, pre-scaled by 1/sqrt(64)=2^-3 (exact; bit-identical scores)
    bf16x8 qa0, qa1;
    {
        const float* qp = Q + ((size_t)b * SLEN + i0w + c) * DIM + g * 8;
        qa0 = pack8s(*(const float4*)(qp),      *(const float4*)(qp + 4),  0.125f);
        qa1 = pack8s(*(const float4*)(qp + 32), *(const float4*)(qp + 36), 0.125f);
    }

    stage_k_panel(Kwb, 0, sK0, w, l);
    // mask -> LDS once (bf16 1.0/0.0); lgkmcnt path only thereafter
    #pragma unroll
    for (int i = 0; i < 8; i++) {
        const int idx = i * NTHR + tid;
        sMaskBf[idx] = Mb[idx] ? (short)0 : (short)0x3F80;
    }
    __syncthreads();

    // ---- Pass A: row sums, K double-buffered across sK0/sK1 ----
    float rsum[4] = {0.f, 0.f, 0.f, 0.f};
    for (int p = 0; p < NPANEL; p++) {
        const short* cur = (p & 1) ? sK1 : sK0;
        if (p < NPANEL - 1)
            stage_k_panel(Kwb, (p + 1) * PANEL, (p & 1) ? sK0 : sK1, w, l);
        const int j0 = p * PANEL;
        #pragma unroll
        for (int jt = 0; jt < 8; jt++) {
            const short* kr = cur + (jt * 16 + c) * DIM;
            bf16x8 kb0 = *(const bf16x8*)(kr + ((g ^ (c & 7)) * 8));
            bf16x8 kb1 = *(const bf16x8*)(kr + (((g + 4) ^ (c & 7)) * 8));
            f32x4 acc = {0.f, 0.f, 0.f, 0.f};
            acc = MFMA16(qa0, kb0, acc);
            acc = MFMA16(qa1, kb1, acc);
            const float em = bf2f((unsigned short)sMaskBf[j0 + jt * 16 + c]);
            #pragma unroll
            for (int r = 0; r < 4; r++)
                rsum[r] += __expf(acc[r]) * em;
        }
        __syncthreads();   // drains next-panel stage (flew under compute)
    }

    // issue pass-B initial K stage; latency hides under the shfl reduce
    stage_k_panel(Kwb, 0, sK0, w, l);

    #pragma unroll
    for (int off = 1; off < 16; off <<= 1) {
        #pragma unroll
        for (int r = 0; r < 4; r++)
            rsum[r] += __shfl_xor(rsum[r], off, 64);
    }
    float scv[4];
    #pragma unroll
    for (int r = 0; r < 4; r++) {
        const bool rm = sMaskBf[i0w + g * 4 + r] == 0;   // row masked?
        scv[r] = (rm || rsum[r] <= 0.f) ? 0.f : 1.f / rsum[r];
    }

    // ---- Pass B: 2-phase, ONE barrier per panel ----
    short* sPw = sP + w * 16 * PROWP;
    f32x4 pv[4];
    #pragma unroll
    for (int nt = 0; nt < 4; nt++) pv[nt] = (f32x4){0.f, 0.f, 0.f, 0.f};

    __syncthreads();   // K0 staged and visible

    for (int p = 0; p < NPANEL; p++) {
        const int j0 = p * PANEL;
        // phase 1: issue next panel's K stage into the other buffer
        if (p < NPANEL - 1)
            stage_k_panel(Kwb, j0 + PANEL, (p & 1) ? sK0 : sK1, w, l);
        const short* kbuf = (p & 1) ? sK1 : sK0;

        // QK -> normalized P (bf16) in per-wave LDS panel
        #pragma unroll
        for (int jt = 0; jt < 8; jt++) {
            const short* kr = kbuf + (jt * 16 + c) * DIM;
            bf16x8 kb0 = *(const bf16x8*)(kr + ((g ^ (c & 7)) * 8));
            bf16x8 kb1 = *(const bf16x8*)(kr + (((g + 4) ^ (c & 7)) * 8));
            f32x4 acc = {0.f, 0.f, 0.f, 0.f};
            acc = MFMA16(qa0, kb0, acc);
            acc = MFMA16(qa1, kb1, acc);
            const float em = bf2f((unsigned short)sMaskBf[j0 + jt * 16 + c]);
            #pragma unroll
            for (int r = 0; r < 4; r++)
                sPw[(g * 4 + r) * PROWP + jt * 16 + c] =
                    f2bf(__expf(acc[r]) * em * scv[r]);
        }
        // PV: A-frag b128 from own P panel; B-frag dense packed L2 load,
        // depth-2 named-register prefetch (R10-verified layout/order)
        {
            const short* vb = Vwb + (size_t)p * 8192 + l * 8;
            bf16x8 v0 = *(const bf16x8*)(vb);
            bf16x8 v1 = *(const bf16x8*)(vb + 512);
            bf16x8 af;
            #pragma unroll
            for (int i = 0; i < 16; i++) {
                bf16x8 cur = v0;
                v0 = v1;
                if (i + 2 < 16) v1 = *(const bf16x8*)(vb + (i + 2) * 512);
                if ((i & 3) == 0)
                    af = *(const bf16x8*)(sPw + c * PROWP + (i >> 2) * 32 + g * 8);
                pv[i & 3] = MFMA16(af, cur, pv[i & 3]);
            }
        }
        // attn write: 16 rows x 32 float4, coalesced, nontemporal
        const size_t rowBase = (size_t)b * SLEN + i0w;
        #pragma unroll
        for (int it = 0; it < 8; it++) {
            const int idx = it * 64 + l;
            const int row = idx >> 5, col4 = idx & 31;
            const unsigned short* pp = (const unsigned short*)sPw + row * PROWP + col4 * 4;
            ushort4 p4 = *(const ushort4*)(pp);
            f32x4 o = {bf2f(p4.x), bf2f(p4.y), bf2f(p4.z), bf2f(p4.w)};
            __builtin_nontemporal_store(o,
                (f32x4*)(outAttn + (rowBase + row) * SLEN + j0 + col4 * 4));
        }
        __syncthreads();   // single per-panel drain: stage + stores
    }

    // ctx write: C-layout direct store (pre-normalized P => no further scale)
    #pragma unroll
    for (int nt = 0; nt < 4; nt++) {
        #pragma unroll
        for (int r = 0; r < 4; r++)
            __builtin_nontemporal_store(pv[nt][r],
                outCtx + ((size_t)b * SLEN + i0w + g * 4 + r) * DIM + nt * 16 + c);
    }
}

// ---------------- fallback: verified R4 kernel (used if ws too small) -----
__global__ __launch_bounds__(NTHR, 3) void sdpa_kernel_fb(
    const float* __restrict__ Q, const float* __restrict__ K,
    const float* __restrict__ V, const int* __restrict__ M,
    float* __restrict__ outCtx, float* __restrict__ outAttn)
{
    __shared__ __align__(16) short sK[128 * PROWK];
    __shared__ __align__(16) short sVT[64 * PROWV];
    __shared__ __align__(16) short sP[NW * 16 * PROWP];
    __shared__ float sMask[PANEL];

    const int tid = threadIdx.x;
    const int w = tid >> 6, l = tid & 63, g = l >> 4, c = l & 15;
    const int b  = blockIdx.x >> 5;
    const int i0 = (blockIdx.x & 31) * TQ;
    const int i0w = i0 + w * 16;

    const float* Kb = K + (size_t)b * SLEN * DIM;
    const float* Vb = V + (size_t)b * SLEN * DIM;
    const int*   Mb = M + b * SLEN;

    bf16x8 qa0, qa1;
    {
        const float* qp = Q + ((size_t)b * SLEN + i0w + c) * DIM + g * 8;
        qa0 = pack8(*(const float4*)(qp),      *(const float4*)(qp + 4));
        qa1 = pack8(*(const float4*)(qp + 32), *(const float4*)(qp + 36));
    }

    const float scl = 0.125f;
    float rsum[4] = {0.f, 0.f, 0.f, 0.f};

    for (int p = 0; p < NPANEL; p++) {
        const int j0 = p * PANEL;
        #pragma unroll
        for (int it = 0; it < 8; it++) {
            const int idx = it * NTHR + tid;
            const int row = idx >> 4, c4 = idx & 15;
            float4 kv = *(const float4*)(Kb + (size_t)(j0 + row) * DIM + c4 * 4);
            *(short4*)(sK + row * PROWK + c4 * 4) =
                make_short4(f2bf(kv.x), f2bf(kv.y), f2bf(kv.z), f2bf(kv.w));
        }
        if (tid < PANEL) sMask[tid] = Mb[j0 + tid] ? 0.f : 1.f;
        __syncthreads();
        #pragma unroll
        for (int jt = 0; jt < 8; jt++) {
            const short* kr = sK + (jt * 16 + c) * PROWK + g * 8;
            bf16x8 kb0 = *(const bf16x8*)(kr);
            bf16x8 kb1 = *(const bf16x8*)(kr + 32);
            f32x4 acc = {0.f, 0.f, 0.f, 0.f};
            acc = MFMA16(qa0, kb0, acc);
            acc = MFMA16(qa1, kb1, acc);
            const float em = sMask[jt * 16 + c];
            #pragma unroll
            for (int r = 0; r < 4; r++)
                rsum[r] += __expf(acc[r] * scl) * em;
        }
        __syncthreads();
    }
    #pragma unroll
    for (int off = 1; off < 16; off <<= 1) {
        #pragma unroll
        for (int r = 0; r < 4; r++)
            rsum[r] += __shfl_xor(rsum[r], off, 64);
    }
    float scv[4];
    #pragma unroll
    for (int r = 0; r < 4; r++) {
        const int rm = Mb[i0w + g * 4 + r];
        scv[r] = (rm || rsum[r] <= 0.f) ? 0.f : 1.f / rsum[r];
    }

    short* sPw = sP + w * 16 * PROWP;
    f32x4 pv[4];
    #pragma unroll
    for (int nt = 0; nt < 4; nt++) pv[nt] = (f32x4){0.f, 0.f, 0.f, 0.f};

    for (int p = 0; p < NPANEL; p++) {
        const int j0 = p * PANEL;
        #pragma unroll
        for (int it = 0; it < 8; it++) {
            const int idx = it * NTHR + tid;
            const int row = idx >> 4, c4 = idx & 15;
            float4 kv = *(const float4*)(Kb + (size_t)(j0 + row) * DIM + c4 * 4);
            *(short4*)(sK + row * PROWK + c4 * 4) =
                make_short4(f2bf(kv.x), f2bf(kv.y), f2bf(kv.z), f2bf(kv.w));
        }
        #pragma unroll
        for (int it = 0; it < 2; it++) {
            const int task = it * NTHR + tid;
            const int k4 = task >> 4, d4g = task & 15;
            const int kb = k4 * 4, d4 = d4g * 4;
            const int colb = kb ^ ((d4g & 3) << 3);
            const float* vp = Vb + (size_t)(j0 + kb) * DIM + d4;
            float4 r0 = *(const float4*)(vp);
            float4 r1 = *(const float4*)(vp + DIM);
            float4 r2 = *(const float4*)(vp + 2 * DIM);
            float4 r3 = *(const float4*)(vp + 3 * DIM);
            *(short4*)(sVT + (d4 + 0) * PROWV + colb) =
                make_short4(f2bf(r0.x), f2bf(r1.x), f2bf(r2.x), f2bf(r3.x));
            *(short4*)(sVT + (d4 + 1) * PROWV + colb) =
                make_short4(f2bf(r0.y), f2bf(r1.y), f2bf(r2.y), f2bf(r3.y));
            *(short4*)(sVT + (d4 + 2) * PROWV + colb) =
                make_short4(f2bf(r0.z), f2bf(r1.z), f2bf(r2.z), f2bf(r3.z));
            *(short4*)(sVT + (d4 + 3) * PROWV + colb) =
                make_short4(f2bf(r0.w), f2bf(r1.w), f2bf(r2.w), f2bf(r3.w));
        }
        if (tid < PANEL) sMask[tid] = Mb[j0 + tid] ? 0.f : 1.f;
        __syncthreads();

        #pragma unroll
        for (int jt = 0; jt < 8; jt++) {
            const short* kr = sK + (jt * 16 + c) * PROWK + g * 8;
            bf16x8 kb0 = *(const bf16x8*)(kr);
            bf16x8 kb1 = *(const bf16x8*)(kr + 32);
            f32x4 acc = {0.f, 0.f, 0.f, 0.f};
            acc = MFMA16(qa0, kb0, acc);
            acc = MFMA16(qa1, kb1, acc);
            const float em = sMask[jt * 16 + c];
            #pragma unroll
            for (int r = 0; r < 4; r++)
                sPw[(g * 4 + r) * PROWP + jt * 16 + c] =
                    f2bf(__expf(acc[r] * scl) * em * scv[r]);
        }
        #pragma unroll
        for (int ks = 0; ks < 4; ks++) {
            bf16x8 af = *(const bf16x8*)(sPw + c * PROWP + ks * 32 + g * 8);
            #pragma unroll
            for (int nt = 0; nt < 4; nt++) {
                const int d = nt * 16 + c;
                const int gp = g ^ ((d >> 2) & 3);
                bf16x8 bfrag = *(const bf16x8*)(sVT + d * PROWV + ks * 32 + gp * 8);
                pv[nt] = MFMA16(af, bfrag, pv[nt]);
            }
        }
        const size_t rowBase = (size_t)b * SLEN + i0w;
        #pragma unroll
        for (int it = 0; it < 8; it++) {
            const int idx = it * 64 + l;
            const int row = idx >> 5, col4 = idx & 31;
            const unsigned short* pp = (const unsigned short*)sPw + row * PROWP + col4 * 4;
            ushort4 p4 = *(const ushort4*)(pp);
            float4 o = {bf2f(p4.x), bf2f(p4.y), bf2f(p4.z), bf2f(p4.w)};
            *(float4*)(outAttn + (rowBase + row) * SLEN + j0 + col4 * 4) = o;
        }
        __syncthreads();
    }

    #pragma unroll
    for (int nt = 0; nt < 4; nt++) {
        #pragma unroll
        for (int r = 0; r < 4; r++)
            outCtx[((size_t)b * SLEN + i0w + g * 4 + r) * DIM + nt * 16 + c] = pv[nt][r];
    }
}

extern "C" void kernel_launch(void* const* d_in, const int* in_sizes, int n_in,
                              void* d_out, int out_size, void* d_ws, size_t ws_size,
                              hipStream_t stream) {
    const float* Q = (const float*)d_in[0];
    const float* K = (const float*)d_in[1];
    const float* V = (const float*)d_in[2];
    const int*   M = (const int*)d_in[3];
    float* outCtx  = (float*)d_out;
    float* outAttn = (float*)d_out + (size_t)NBATCH * SLEN * DIM;
    dim3 grid(NBATCH * (SLEN / TQ));   // 512 blocks

    const size_t nElem = (size_t)NBATCH * SLEN * DIM;      // 2,097,152
    const size_t wsNeed = nElem * 2 * sizeof(short);       // 8 MB
    if (d_ws != nullptr && ws_size >= wsNeed) {
        short* Kws = (short*)d_ws;
        short* Vpp = Kws + nElem;
        preconvert_kernel<<<dim3(NBATCH * NPANEL), 256, 0, stream>>>(K, V, Kws, Vpp);
        sdpa_kernel<<<grid, NTHR, 0, stream>>>(Q, Kws, Vpp, M, outCtx, outAttn);
    } else {
        sdpa_kernel_fb<<<grid, NTHR, 0, stream>>>(Q, K, V, M, outCtx, outAttn);
    }
}